// Round 1
// baseline (72.235 us; speedup 1.0000x reference)
//
#include <hip/hip_runtime.h>

#define N_ROWS 128
#define IN_DIM 1024
#define OUT_DIM 1024

// out[n,o] = max_k(w[o,k] + x[n,k]) + bias[o]   (tropical matmul)
//
// R1 restructure: 4 o-rows per lane (was 1) -> 24 VALU per ds_read_b128
// (was 6). Rationale: ds_read_b128 costs ~12 cyc/CU (shared pipe) while
// 6 VALU cost only 3 cyc/CU-equivalent (4 SIMDs) -> old kernel was 4x
// LDS-issue-bound. Now LDS (12 cyc) == VALU (24*2/4 = 12 cyc) balanced.
//
// Wave tile: 8n x 16o. Lane = (og, g): g = k-phase 0..15 (float4 kq =
//   t*16+g), og -> 4 w-rows obase..obase+3. Block: 4 waves = 8n x 64o.
// Grid: 16 n-blocks x 16 o-blocks = 256 blocks = 1 block/CU, 1 wave/SIMD.
//   blockIdx%8 == bo%8 -> all 16 blocks sharing an o-panel land on one
//   XCD; w working set per XCD = 2 panels * 256 KB = 512 KB (L2-fit).
// Latency hiding at 1 wave/SIMD is pure ILP: 32 indep acc chains +
//   explicit double-buffer of x (LDS->reg, 1 step ahead) and w
//   (global->reg, reloaded right after use, ~1.5 steps ahead).
// Epilogue: butterfly max over g (xor 1,2,4,8) leaves identical results
//   in all 16 g-lanes -> redistribute so every lane stores one float2.

__global__ __launch_bounds__(256, 1)
void tropical_linear_kernel(const float* __restrict__ x,
                            const float* __restrict__ w,
                            const float* __restrict__ bias,
                            float* __restrict__ out) {
    __shared__ float4 xs[8 * 256];   // 32 KB

    const int tid  = threadIdx.x;
    const int wid  = tid >> 6;       // wave 0..3
    const int lane = tid & 63;
    const int g    = lane & 15;      // k phase 0..15
    const int og   = lane >> 4;      // o group 0..3

    const int bn = blockIdx.x >> 4;  // 16 n-blocks
    const int bo = blockIdx.x & 15;  // 16 o-blocks (idx%8==bo%8 -> same XCD)
    const int n0 = bn * 8;
    const int obase = bo * 64 + wid * 16 + og * 4;

    const float4* __restrict__ x4 = (const float4*)x;

    // w row pointers (row stride 4096 B > 13-bit imm, so 4 bases; the
    // 16 k-steps per row fold into imm offsets t*256 <= 3840).
    const float4* __restrict__ wp0 = (const float4*)w + (size_t)(obase + 0) * 256 + g;
    const float4* __restrict__ wp1 = (const float4*)w + (size_t)(obase + 1) * 256 + g;
    const float4* __restrict__ wp2 = (const float4*)w + (size_t)(obase + 2) * 256 + g;
    const float4* __restrict__ wp3 = (const float4*)w + (size_t)(obase + 3) * 256 + g;

    // ---- stage x tile: 2048 float4, 8 per thread, coalesced ----
#pragma unroll
    for (int i = 0; i < 8; ++i) {
        const int idx = tid + i * 256;
        xs[idx] = x4[(size_t)(n0 + (idx >> 8)) * 256 + (idx & 255)];
    }

    // w prologue loads (t=0,1) issued before the barrier: independent of LDS
    float4 wA[4], wB[4];
    wA[0] = wp0[0];  wA[1] = wp1[0];  wA[2] = wp2[0];  wA[3] = wp3[0];
    wB[0] = wp0[16]; wB[1] = wp1[16]; wB[2] = wp2[16]; wB[3] = wp3[16];

    float acc[8][4];
#pragma unroll
    for (int j = 0; j < 8; ++j)
#pragma unroll
        for (int r = 0; r < 4; ++r) acc[j][r] = -3.4e38f;

    __syncthreads();

    const float4* __restrict__ xsg = xs + g;

    float4 xA[8], xB[8];
#pragma unroll
    for (int j = 0; j < 8; ++j) xA[j] = xsg[j * 256];    // t=0

#define TROPIC_STEP(WBUF, XBUF)                                   \
    _Pragma("unroll")                                             \
    for (int j = 0; j < 8; ++j) {                                 \
        const float4 xv = XBUF[j];                                \
        _Pragma("unroll")                                         \
        for (int r = 0; r < 4; ++r) {                             \
            const float s0 = WBUF[r].x + xv.x;                    \
            const float s1 = WBUF[r].y + xv.y;                    \
            const float s2 = WBUF[r].z + xv.z;                    \
            const float s3 = WBUF[r].w + xv.w;                    \
            const float m = fmaxf(fmaxf(s0, s1), s2);             \
            acc[j][r] = fmaxf(fmaxf(m, s3), acc[j][r]);           \
        }                                                         \
    }

    // Steady state: 7 iterations x 2 k-steps; tail handles t=14,15.
#pragma unroll 1
    for (int tt = 0; tt < 7; ++tt) {
        const int t0 = 2 * tt;
        // ---- step t0: consume (wA, xA) ----
#pragma unroll
        for (int j = 0; j < 8; ++j) xB[j] = xsg[j * 256 + (t0 + 1) * 16];
        TROPIC_STEP(wA, xA)
        // reload wA for t0+2 right after last use -> no reg copies
        wA[0] = wp0[(t0 + 2) * 16]; wA[1] = wp1[(t0 + 2) * 16];
        wA[2] = wp2[(t0 + 2) * 16]; wA[3] = wp3[(t0 + 2) * 16];
        // ---- step t1: consume (wB, xB) ----
#pragma unroll
        for (int j = 0; j < 8; ++j) xA[j] = xsg[j * 256 + (t0 + 2) * 16];
        TROPIC_STEP(wB, xB)
        wB[0] = wp0[(t0 + 3) * 16]; wB[1] = wp1[(t0 + 3) * 16];
        wB[2] = wp2[(t0 + 3) * 16]; wB[3] = wp3[(t0 + 3) * 16];
    }
    // ---- tail: t=14 (wA,xA), t=15 (wB,xB) ----
#pragma unroll
    for (int j = 0; j < 8; ++j) xB[j] = xsg[j * 256 + 15 * 16];
    TROPIC_STEP(wA, xA)
    TROPIC_STEP(wB, xB)

#undef TROPIC_STEP

    // ---- reduce across the 16 k-phases (lane bits 0..3) ----
    // After the butterfly every g-lane in an og group holds identical
    // acc[j][r]; lane g stores (j = g&7, col pair = (g>>3)*2).
    const int jj   = g & 7;
    const int half = g >> 3;
    float2 res = make_float2(0.f, 0.f);
#pragma unroll
    for (int j = 0; j < 8; ++j) {
#pragma unroll
        for (int r = 0; r < 4; ++r) {
            float v = acc[j][r];
            v = fmaxf(v, __shfl_xor(v, 1, 64));
            v = fmaxf(v, __shfl_xor(v, 2, 64));
            v = fmaxf(v, __shfl_xor(v, 4, 64));
            v = fmaxf(v, __shfl_xor(v, 8, 64));
            acc[j][r] = v;
        }
        if (jj == j) {   // static indices only (no runtime array index)
            res.x = half ? acc[j][2] : acc[j][0];
            res.y = half ? acc[j][3] : acc[j][1];
        }
    }
    const int oc = obase + half * 2;
    const float2 bv = *(const float2*)&bias[oc];
    res.x += bv.x;
    res.y += bv.y;
    *(float2*)&out[(size_t)(n0 + jj) * OUT_DIM + oc] = res;
}

extern "C" void kernel_launch(void* const* d_in, const int* in_sizes, int n_in,
                              void* d_out, int out_size, void* d_ws, size_t ws_size,
                              hipStream_t stream) {
    const float* x    = (const float*)d_in[0];   // [128,1024]
    const float* w    = (const float*)d_in[1];   // [1024,1024]
    const float* bias = (const float*)d_in[2];   // [1024]
    float* out = (float*)d_out;                  // [128,1024]

    dim3 grid(256);
    dim3 block(256);
    hipLaunchKernelGGL(tropical_linear_kernel, grid, block, 0, stream, x, w, bias, out);
}

// Round 2
// 72.144 us; speedup vs baseline: 1.0013x; 1.0013x over previous
//
#include <hip/hip_runtime.h>

#define N_ROWS 128
#define IN_DIM 1024
#define OUT_DIM 1024

// out[n,o] = max_k(w[o,k] + x[n,k]) + bias[o]   (tropical matmul)
//
// R2: restore TLP while keeping R1's VALU:LDS parity.
// Per-CU accounting: LDS:VALU demand = 4:r (r = o-rows per lane),
// independent of wave count. r=4 keeps parity; shrinking the n-tile
// 8 -> 4 doubles the grid: 32 n-blocks x 16 o-blocks = 512 blocks =
// 2 blocks/CU = 8 waves/CU (2 waves/SIMD) -> stalls hidden by TLP,
// which R1 (1 wave/SIMD) lacked (72.2 vs 66.9 regression).
//
// Wave tile: 4n x 16o. Lane = (og, g): g = k-phase 0..15 (float4
//   kq = t*16+g), og -> 4 w-rows obase..obase+3. Block: 4 waves = 4n x 64o.
// LDS: 4 rows x 4 KB = 16 KB/block (2 blocks = 32 KB/CU <= 160).
// VGPR ~105 (acc 16 + x 32 + w 32 + addr) -> 2 blocks/CU legal;
//   __launch_bounds__(256,2) enforces the cap.
// w traffic: 512 blocks x 256 KB = 134 MB, L2-resident (512 KB/XCD via
//   blockIdx%8 == bo%8 XCD affinity) -> ~13 TB/s aggregate, under ceiling.
// Double-buffered x (LDS->reg) and w (global->reg) as in R1.

__global__ __launch_bounds__(256, 2)
void tropical_linear_kernel(const float* __restrict__ x,
                            const float* __restrict__ w,
                            const float* __restrict__ bias,
                            float* __restrict__ out) {
    __shared__ float4 xs[4 * 256];   // 16 KB

    const int tid  = threadIdx.x;
    const int wid  = tid >> 6;       // wave 0..3
    const int lane = tid & 63;
    const int g    = lane & 15;      // k phase 0..15
    const int og   = lane >> 4;      // o group 0..3

    const int bn = blockIdx.x >> 4;  // 32 n-blocks
    const int bo = blockIdx.x & 15;  // 16 o-blocks (idx%8==bo%8 -> same XCD)
    const int n0 = bn * 4;
    const int obase = bo * 64 + wid * 16 + og * 4;

    const float4* __restrict__ x4 = (const float4*)x;

    // w row pointers (row stride 4096 B > 13-bit imm, so 4 bases; the
    // 16 k-steps per row fold into imm offsets t*256 <= 3840).
    const float4* __restrict__ wp0 = (const float4*)w + (size_t)(obase + 0) * 256 + g;
    const float4* __restrict__ wp1 = (const float4*)w + (size_t)(obase + 1) * 256 + g;
    const float4* __restrict__ wp2 = (const float4*)w + (size_t)(obase + 2) * 256 + g;
    const float4* __restrict__ wp3 = (const float4*)w + (size_t)(obase + 3) * 256 + g;

    // ---- stage x tile: 1024 float4, 4 per thread, coalesced ----
#pragma unroll
    for (int i = 0; i < 4; ++i) {
        const int idx = tid + i * 256;
        xs[idx] = x4[(size_t)(n0 + (idx >> 8)) * 256 + (idx & 255)];
    }

    // w prologue loads (t=0,1) issued before the barrier: independent of LDS
    float4 wA[4], wB[4];
    wA[0] = wp0[0];  wA[1] = wp1[0];  wA[2] = wp2[0];  wA[3] = wp3[0];
    wB[0] = wp0[16]; wB[1] = wp1[16]; wB[2] = wp2[16]; wB[3] = wp3[16];

    float acc[4][4];
#pragma unroll
    for (int j = 0; j < 4; ++j)
#pragma unroll
        for (int r = 0; r < 4; ++r) acc[j][r] = -3.4e38f;

    __syncthreads();

    const float4* __restrict__ xsg = xs + g;

    float4 xA[4], xB[4];
#pragma unroll
    for (int j = 0; j < 4; ++j) xA[j] = xsg[j * 256];    // t=0

#define TROPIC_STEP(WBUF, XBUF)                                   \
    _Pragma("unroll")                                             \
    for (int j = 0; j < 4; ++j) {                                 \
        const float4 xv = XBUF[j];                                \
        _Pragma("unroll")                                         \
        for (int r = 0; r < 4; ++r) {                             \
            const float s0 = WBUF[r].x + xv.x;                    \
            const float s1 = WBUF[r].y + xv.y;                    \
            const float s2 = WBUF[r].z + xv.z;                    \
            const float s3 = WBUF[r].w + xv.w;                    \
            const float m = fmaxf(fmaxf(s0, s1), s2);             \
            acc[j][r] = fmaxf(fmaxf(m, s3), acc[j][r]);           \
        }                                                         \
    }

    // Steady state: 7 iterations x 2 k-steps; tail handles t=14,15.
#pragma unroll 1
    for (int tt = 0; tt < 7; ++tt) {
        const int t0 = 2 * tt;
        // ---- step t0: consume (wA, xA) ----
#pragma unroll
        for (int j = 0; j < 4; ++j) xB[j] = xsg[j * 256 + (t0 + 1) * 16];
        TROPIC_STEP(wA, xA)
        // reload wA for t0+2 right after last use -> no reg copies
        wA[0] = wp0[(t0 + 2) * 16]; wA[1] = wp1[(t0 + 2) * 16];
        wA[2] = wp2[(t0 + 2) * 16]; wA[3] = wp3[(t0 + 2) * 16];
        // ---- step t1: consume (wB, xB) ----
#pragma unroll
        for (int j = 0; j < 4; ++j) xA[j] = xsg[j * 256 + (t0 + 2) * 16];
        TROPIC_STEP(wB, xB)
        wB[0] = wp0[(t0 + 3) * 16]; wB[1] = wp1[(t0 + 3) * 16];
        wB[2] = wp2[(t0 + 3) * 16]; wB[3] = wp3[(t0 + 3) * 16];
    }
    // ---- tail: t=14 (wA,xA), t=15 (wB,xB) ----
#pragma unroll
    for (int j = 0; j < 4; ++j) xB[j] = xsg[j * 256 + 15 * 16];
    TROPIC_STEP(wA, xA)
    TROPIC_STEP(wB, xB)

#undef TROPIC_STEP

    // ---- reduce across the 16 k-phases (lane bits 0..3) ----
    // After the butterfly every g-lane in an og group holds identical
    // acc[j][r]; redistribute: lanes g<8 each store one float2:
    //   j = g&3, col pair pr = g>>3 ... here g<8: j = g&3, pr = (g>>2)&1.
#pragma unroll
    for (int j = 0; j < 4; ++j) {
#pragma unroll
        for (int r = 0; r < 4; ++r) {
            float v = acc[j][r];
            v = fmaxf(v, __shfl_xor(v, 1, 64));
            v = fmaxf(v, __shfl_xor(v, 2, 64));
            v = fmaxf(v, __shfl_xor(v, 4, 64));
            v = fmaxf(v, __shfl_xor(v, 8, 64));
            acc[j][r] = v;
        }
    }

    if (g < 8) {
        const int jj = g & 3;        // n-row within tile
        const int pr = (g >> 2) & 1; // which float2 column pair
        float2 res = make_float2(0.f, 0.f);
#pragma unroll
        for (int j = 0; j < 4; ++j) {
            if (jj == j) {           // static indices only
                res.x = pr ? acc[j][2] : acc[j][0];
                res.y = pr ? acc[j][3] : acc[j][1];
            }
        }
        const int oc = obase + pr * 2;
        const float2 bv = *(const float2*)&bias[oc];
        res.x += bv.x;
        res.y += bv.y;
        *(float2*)&out[(size_t)(n0 + jj) * OUT_DIM + oc] = res;
    }
}

extern "C" void kernel_launch(void* const* d_in, const int* in_sizes, int n_in,
                              void* d_out, int out_size, void* d_ws, size_t ws_size,
                              hipStream_t stream) {
    const float* x    = (const float*)d_in[0];   // [128,1024]
    const float* w    = (const float*)d_in[1];   // [1024,1024]
    const float* bias = (const float*)d_in[2];   // [1024]
    float* out = (float*)d_out;                  // [128,1024]

    dim3 grid(512);
    dim3 block(256);
    hipLaunchKernelGGL(tropical_linear_kernel, grid, block, 0, stream, x, w, bias, out);
}

// Round 3
// 71.769 us; speedup vs baseline: 1.0065x; 1.0052x over previous
//
#include <hip/hip_runtime.h>

#define N_ROWS 128
#define IN_DIM 1024
#define OUT_DIM 1024

// out[n,o] = max_k(w[o,k] + x[n,k]) + bias[o]   (tropical matmul)
//
// R3: max-TLP at constant VALU:LDS parity — the H1/H2 discriminator.
// Data points: old kernel 16 waves/CU -> 66.9; R1 4 w/CU -> 72.24;
// R2 8 w/CU -> 72.14. If latency-bound (H1), TLP is the lever; this
// round hits 16 waves/CU while keeping R1's 4-o-rows-per-lane LDS
// amortization (24 VALU per ds_read_b128; the ratio is n-tile-invariant).
//
// Wave tile: 2n x 16o. Lane = (og, g): g = k-phase 0..15 (float4
//   kq = t*16+g), og -> 4 w-rows obase..obase+3. Block: 4 waves = 2n x 64o.
// Grid: 64 n-blocks x 16 o-blocks = 1024 blocks = 4 blocks/CU
//   = 16 waves/CU (4 waves/SIMD). LDS 8 KB/block -> 32 KB/CU.
//   VGPR ~80 -> __launch_bounds__(256,4) legal (needs <=128).
// w traffic: 1024 blocks x 256 KB = 268 MB from L2 (32 MB/XCD;
//   bo = idx&15, idx%8==bo%8 -> same-bo same-XCD, 512 KB w resident/XCD).
// Double-buffered x (LDS->reg) and w (global->reg, reload right after
//   consumption = 2-step lead); 4 waves/SIMD TLP covers the rest.

__global__ __launch_bounds__(256, 4)
void tropical_linear_kernel(const float* __restrict__ x,
                            const float* __restrict__ w,
                            const float* __restrict__ bias,
                            float* __restrict__ out) {
    __shared__ float4 xs[2 * 256];   // 8 KB

    const int tid  = threadIdx.x;
    const int wid  = tid >> 6;       // wave 0..3
    const int lane = tid & 63;
    const int g    = lane & 15;      // k phase 0..15
    const int og   = lane >> 4;      // o group 0..3

    const int bn = blockIdx.x >> 4;  // 64 n-blocks
    const int bo = blockIdx.x & 15;  // 16 o-blocks (idx%8==bo%8 -> same XCD)
    const int n0 = bn * 2;
    const int obase = bo * 64 + wid * 16 + og * 4;

    const float4* __restrict__ x4 = (const float4*)x;

    // ---- stage x tile: 512 float4, 2 per thread, coalesced ----
    // (before w prologue: staging is on the critical path for all waves)
#pragma unroll
    for (int i = 0; i < 2; ++i) {
        const int idx = tid + i * 256;
        xs[idx] = x4[(size_t)(n0 + (idx >> 8)) * 256 + (idx & 255)];
    }

    // w row pointers (row stride 4096 B > 13-bit imm, so 4 bases; the
    // 16 k-steps per row fold into imm offsets t*256 <= 3840).
    const float4* __restrict__ wp0 = (const float4*)w + (size_t)(obase + 0) * 256 + g;
    const float4* __restrict__ wp1 = (const float4*)w + (size_t)(obase + 1) * 256 + g;
    const float4* __restrict__ wp2 = (const float4*)w + (size_t)(obase + 2) * 256 + g;
    const float4* __restrict__ wp3 = (const float4*)w + (size_t)(obase + 3) * 256 + g;

    // w prologue loads (t=0,1) issued before the barrier: independent of LDS
    float4 wA[4], wB[4];
    wA[0] = wp0[0];  wA[1] = wp1[0];  wA[2] = wp2[0];  wA[3] = wp3[0];
    wB[0] = wp0[16]; wB[1] = wp1[16]; wB[2] = wp2[16]; wB[3] = wp3[16];

    float acc[2][4];
#pragma unroll
    for (int j = 0; j < 2; ++j)
#pragma unroll
        for (int r = 0; r < 4; ++r) acc[j][r] = -3.4e38f;

    __syncthreads();

    const float4* __restrict__ xsg = xs + g;

    float4 xA[2], xB[2];
#pragma unroll
    for (int j = 0; j < 2; ++j) xA[j] = xsg[j * 256];    // t=0

#define TROPIC_STEP(WBUF, XBUF)                                   \
    _Pragma("unroll")                                             \
    for (int j = 0; j < 2; ++j) {                                 \
        const float4 xv = XBUF[j];                                \
        _Pragma("unroll")                                         \
        for (int r = 0; r < 4; ++r) {                             \
            const float s0 = WBUF[r].x + xv.x;                    \
            const float s1 = WBUF[r].y + xv.y;                    \
            const float s2 = WBUF[r].z + xv.z;                    \
            const float s3 = WBUF[r].w + xv.w;                    \
            const float m = fmaxf(fmaxf(s0, s1), s2);             \
            acc[j][r] = fmaxf(fmaxf(m, s3), acc[j][r]);           \
        }                                                         \
    }

    // Steady state: 7 iterations x 2 k-steps; tail handles t=14,15.
#pragma unroll 1
    for (int tt = 0; tt < 7; ++tt) {
        const int t0 = 2 * tt;
        // ---- step t0: consume (wA, xA) ----
#pragma unroll
        for (int j = 0; j < 2; ++j) xB[j] = xsg[j * 256 + (t0 + 1) * 16];
        TROPIC_STEP(wA, xA)
        // reload wA for t0+2 right after last use (2-step lead)
        wA[0] = wp0[(t0 + 2) * 16]; wA[1] = wp1[(t0 + 2) * 16];
        wA[2] = wp2[(t0 + 2) * 16]; wA[3] = wp3[(t0 + 2) * 16];
        // ---- step t1: consume (wB, xB) ----
#pragma unroll
        for (int j = 0; j < 2; ++j) xA[j] = xsg[j * 256 + (t0 + 2) * 16];
        TROPIC_STEP(wB, xB)
        wB[0] = wp0[(t0 + 3) * 16]; wB[1] = wp1[(t0 + 3) * 16];
        wB[2] = wp2[(t0 + 3) * 16]; wB[3] = wp3[(t0 + 3) * 16];
    }
    // ---- tail: t=14 (wA,xA), t=15 (wB,xB) ----
#pragma unroll
    for (int j = 0; j < 2; ++j) xB[j] = xsg[j * 256 + 15 * 16];
    TROPIC_STEP(wA, xA)
    TROPIC_STEP(wB, xB)

#undef TROPIC_STEP

    // ---- reduce across the 16 k-phases (lane bits 0..3) ----
#pragma unroll
    for (int j = 0; j < 2; ++j) {
#pragma unroll
        for (int r = 0; r < 4; ++r) {
            float v = acc[j][r];
            v = fmaxf(v, __shfl_xor(v, 1, 64));
            v = fmaxf(v, __shfl_xor(v, 2, 64));
            v = fmaxf(v, __shfl_xor(v, 4, 64));
            v = fmaxf(v, __shfl_xor(v, 8, 64));
            acc[j][r] = v;
        }
    }

    // After the butterfly all 16 g-lanes in an og group hold identical
    // acc; lanes g<4 each store one float2: j = g&1, col pair pr = g>>1.
    if (g < 4) {
        const int jj = g & 1;        // n-row within tile
        const int pr = g >> 1;       // which float2 column pair
        float2 res = make_float2(0.f, 0.f);
#pragma unroll
        for (int j = 0; j < 2; ++j) {
            if (jj == j) {           // static indices only
                res.x = pr ? acc[j][2] : acc[j][0];
                res.y = pr ? acc[j][3] : acc[j][1];
            }
        }
        const int oc = obase + pr * 2;
        const float2 bv = *(const float2*)&bias[oc];
        res.x += bv.x;
        res.y += bv.y;
        *(float2*)&out[(size_t)(n0 + jj) * OUT_DIM + oc] = res;
    }
}

extern "C" void kernel_launch(void* const* d_in, const int* in_sizes, int n_in,
                              void* d_out, int out_size, void* d_ws, size_t ws_size,
                              hipStream_t stream) {
    const float* x    = (const float*)d_in[0];   // [128,1024]
    const float* w    = (const float*)d_in[1];   // [1024,1024]
    const float* bias = (const float*)d_in[2];   // [1024]
    float* out = (float*)d_out;                  // [128,1024]

    dim3 grid(1024);
    dim3 block(256);
    hipLaunchKernelGGL(tropical_linear_kernel, grid, block, 0, stream, x, w, bias, out);
}